// Round 2
// baseline (138.662 us; speedup 1.0000x reference)
//
#include <hip/hip_runtime.h>
#include <hip/hip_bf16.h>
#include <stdint.h>

#define BB 4
#define NN 2048
#define FF 128

typedef __attribute__((ext_vector_type(8))) short bf16x8;
typedef __attribute__((ext_vector_type(4))) float f32x4;

__device__ inline unsigned pk_bf16(float a, float b) {
    union { float f; unsigned u; } x, y;
    x.f = a; y.f = b;
    unsigned xu = x.u + (0x7fffu + ((x.u >> 16) & 1u));
    unsigned yu = y.u + (0x7fffu + ((y.u >> 16) & 1u));
    return (xu >> 16) | (yu & 0xffff0000u);
}

#define XT_P 136
#define WT_P 136

// ---------------- Kernel 1: h = x@W via bf16 MFMA, s = h@a_w + a_b, Ht bf16 ---------
// (unchanged — verified)
__global__ __launch_bounds__(256) void k1_proj(
    const float* __restrict__ x, const float* __restrict__ W,
    const float* __restrict__ a_w, const float* __restrict__ a_b,
    uint16_t* __restrict__ Ht, float* __restrict__ s_out)
{
    __shared__ uint16_t xt[16 * XT_P];
    __shared__ uint16_t Wt[128 * WT_P];
    __shared__ float sredw[4 * 16];

    const int t = threadIdx.x;
    const int w = t >> 6, l = t & 63;
    const int m16 = l & 15, q = l >> 4;
    const int b = blockIdx.x >> 7;
    const int n0 = (blockIdx.x & 127) << 4;

    const int c4 = (t & 31) * 4, kh = (t >> 5) * 16;
    float4 wr0[8], wr1[8];
    #pragma unroll
    for (int kk = 0; kk < 8; ++kk) {
        const int k = kh + 2 * kk;
        wr0[kk] = *(const float4*)(W + (size_t)k * 128 + c4);
        wr1[kk] = *(const float4*)(W + (size_t)(k + 1) * 128 + c4);
    }
    {
        const int row = t >> 4, c0 = (t & 15) * 8;
        const float* xr = x + ((size_t)(b * NN + n0 + row)) * FF + c0;
        const float4 v0 = *(const float4*)xr;
        const float4 v1 = *(const float4*)(xr + 4);
        unsigned* dst = (unsigned*)(xt + row * XT_P + c0);
        dst[0] = pk_bf16(v0.x, v0.y); dst[1] = pk_bf16(v0.z, v0.w);
        dst[2] = pk_bf16(v1.x, v1.y); dst[3] = pk_bf16(v1.z, v1.w);
    }
    #pragma unroll
    for (int kk = 0; kk < 8; ++kk) {
        const int k = kh + 2 * kk;
        *(unsigned*)(Wt + (c4 + 0) * WT_P + k) = pk_bf16(wr0[kk].x, wr1[kk].x);
        *(unsigned*)(Wt + (c4 + 1) * WT_P + k) = pk_bf16(wr0[kk].y, wr1[kk].y);
        *(unsigned*)(Wt + (c4 + 2) * WT_P + k) = pk_bf16(wr0[kk].z, wr1[kk].z);
        *(unsigned*)(Wt + (c4 + 3) * WT_P + k) = pk_bf16(wr0[kk].w, wr1[kk].w);
    }
    const int g0 = (2 * w) * 16 + m16, g1 = (2 * w + 1) * 16 + m16;
    const float aw0 = a_w[g0], aw1 = a_w[g1];
    __syncthreads();

    f32x4 acc0 = {}, acc1 = {};
    bf16x8 af[4];
    #pragma unroll
    for (int dk = 0; dk < 4; ++dk)
        af[dk] = *(const bf16x8*)(xt + m16 * XT_P + dk * 32 + q * 8);
    #pragma unroll
    for (int dk = 0; dk < 4; ++dk) {
        bf16x8 b0 = *(const bf16x8*)(Wt + g0 * WT_P + dk * 32 + q * 8);
        bf16x8 b1 = *(const bf16x8*)(Wt + g1 * WT_P + dk * 32 + q * 8);
        acc0 = __builtin_amdgcn_mfma_f32_16x16x32_bf16(af[dk], b0, acc0, 0, 0, 0);
        acc1 = __builtin_amdgcn_mfma_f32_16x16x32_bf16(af[dk], b1, acc1, 0, 0, 0);
    }

    float sp[4];
    #pragma unroll
    for (int r = 0; r < 4; ++r) sp[r] = acc0[r] * aw0 + acc1[r] * aw1;
    #pragma unroll
    for (int off = 1; off < 16; off <<= 1)
        #pragma unroll
        for (int r = 0; r < 4; ++r) sp[r] += __shfl_xor(sp[r], off, 64);
    if (m16 == 0) {
        #pragma unroll
        for (int r = 0; r < 4; ++r) sredw[w * 16 + q * 4 + r] = sp[r];
    }
    {
        uint2 o0 = { pk_bf16(acc0[0], acc0[1]), pk_bf16(acc0[2], acc0[3]) };
        uint2 o1 = { pk_bf16(acc1[0], acc1[1]), pk_bf16(acc1[2], acc1[3]) };
        *(uint2*)(Ht + ((size_t)(b * 128 + g0)) * NN + n0 + q * 4) = o0;
        *(uint2*)(Ht + ((size_t)(b * 128 + g1)) * NN + n0 + q * 4) = o1;
    }
    __syncthreads();
    if (t < 16)
        s_out[b * NN + n0 + t] = sredw[t] + sredw[16 + t] + sredw[32 + t] + sredw[48 + t] + a_b[0];
}

// ---------------- Kernel 2: fused full-row attention ------------------------------
// Grid: is(128) x b(4) = 512 blocks (2/CU), 256 thr (4 waves).
// Block owns 16 i-rows x the FULL 2048-j range. Per round (8 rounds x 256 j):
// wave w handles j-chunks {w*32, w*32+128} of the window; A read once from HBM
// (1-round reg prefetch); h-frags re-read per round from L2-resident Ht (2 MB);
// P never leaves the wave; O and rowsum accumulate in REGISTERS across all
// rounds (f32). ONE barrier + one LDS cross-wave reduce at the end, then
// normalize, add bias, write final f32 out. No po/prs workspace, no k3.
// NOTE: P->bf16 packing uses the round-0-verified pk_bf16 bit-trick; the
// v_cvt_pk_bf16_f32 inline-asm variant failed refcheck (absmax 0.29).
__global__ __launch_bounds__(256, 2) void k2_attn(
    const float* __restrict__ A, const uint16_t* __restrict__ Ht,
    const float* __restrict__ s, const float* __restrict__ bias,
    float* __restrict__ out)
{
    __shared__ float Opw[4][16 * 132];   // stride 132 -> conflict-free f32x4 RW
    __shared__ float rsw[4][16];

    const int t = threadIdx.x;
    const int w = t >> 6, l = t & 63;
    const int m16 = l & 15, q = l >> 4;

    const int is = blockIdx.x & 127;
    const int b  = blockIdx.x >> 7;
    const int ibase = is * 16;

    const float* sb = s + b * NN;
    const float* Ab = A + (size_t)b * NN * NN;
    const uint16_t* Hb = Ht + (size_t)b * FF * NN;

    const float si = sb[ibase + m16];                 // loop-invariant
    const float* Ar = Ab + (size_t)(ibase + m16) * NN;

    const int co = w * 32 + q * 8;    // this lane's chunk offset in the 256-j window

    // round-0 prefetch: A (HBM) + sj (L2)
    float4 a00 = *(const float4*)(Ar + co);
    float4 a01 = *(const float4*)(Ar + co + 4);
    float4 a10 = *(const float4*)(Ar + co + 128);
    float4 a11 = *(const float4*)(Ar + co + 132);
    float4 sj00 = *(const float4*)(sb + co);
    float4 sj01 = *(const float4*)(sb + co + 4);
    float4 sj10 = *(const float4*)(sb + co + 128);
    float4 sj11 = *(const float4*)(sb + co + 132);

    f32x4 acc[8];
    #pragma unroll
    for (int gt = 0; gt < 8; ++gt) acc[gt] = (f32x4){0.f, 0.f, 0.f, 0.f};
    float rs = 0.f;

    #pragma unroll
    for (int r = 0; r < 8; ++r) {
        const int jc0 = r * 256 + co;
        const int jc1 = jc0 + 128;

        // h-fragments for this round (L2-resident Ht; issued early, consumed
        // by MFMAs after the pv/exp phase -> latency covered)
        bf16x8 hf0[8], hf1[8];
        #pragma unroll
        for (int gt = 0; gt < 8; ++gt) {
            const uint16_t* hp = Hb + (size_t)(gt * 16 + m16) * NN;
            hf0[gt] = *(const bf16x8*)(hp + jc0);
            hf1[gt] = *(const bf16x8*)(hp + jc1);
        }

        // next-round A + sj prefetch (compile-time guarded: full unroll)
        float4 n00, n01, n10, n11, t00, t01, t10, t11;
        if (r < 7) {
            const int jn = jc0 + 256;
            n00 = *(const float4*)(Ar + jn);
            n01 = *(const float4*)(Ar + jn + 4);
            n10 = *(const float4*)(Ar + jn + 128);
            n11 = *(const float4*)(Ar + jn + 132);
            t00 = *(const float4*)(sb + jn);
            t01 = *(const float4*)(sb + jn + 4);
            t10 = *(const float4*)(sb + jn + 128);
            t11 = *(const float4*)(sb + jn + 132);
        }

        const float svv[16] = {sj00.x,sj00.y,sj00.z,sj00.w, sj01.x,sj01.y,sj01.z,sj01.w,
                               sj10.x,sj10.y,sj10.z,sj10.w, sj11.x,sj11.y,sj11.z,sj11.w};
        const float avv[16] = {a00.x,a00.y,a00.z,a00.w, a01.x,a01.y,a01.z,a01.w,
                               a10.x,a10.y,a10.z,a10.w, a11.x,a11.y,a11.z,a11.w};
        float pv[16];
        #pragma unroll
        for (int j = 0; j < 16; ++j) {
            float e = si + svv[j];
            e = fmaxf(e, 0.2f * e);               // LeakyReLU(0.2)
            pv[j] = __expf(e + avv[j]);
            rs += pv[j];
        }
        union { unsigned u[4]; bf16x8 v; } fa0, fa1;
        #pragma unroll
        for (int j = 0; j < 4; ++j) {
            fa0.u[j] = pk_bf16(pv[2 * j], pv[2 * j + 1]);
            fa1.u[j] = pk_bf16(pv[8 + 2 * j], pv[9 + 2 * j]);
        }

        // 16 MFMAs: accumulate this wave's P x all 128 g into persistent acc
        #pragma unroll
        for (int gt = 0; gt < 8; ++gt) {
            acc[gt] = __builtin_amdgcn_mfma_f32_16x16x32_bf16(fa0.v, hf0[gt], acc[gt], 0, 0, 0);
            acc[gt] = __builtin_amdgcn_mfma_f32_16x16x32_bf16(fa1.v, hf1[gt], acc[gt], 0, 0, 0);
        }

        if (r < 7) {
            a00 = n00; a01 = n01; a10 = n10; a11 = n11;
            sj00 = t00; sj01 = t01; sj10 = t10; sj11 = t11;
        }
    }

    // ---- single cross-wave reduce + normalize + bias + store ----
    rs += __shfl_xor(rs, 16, 64);
    rs += __shfl_xor(rs, 32, 64);
    if (q == 0) rsw[w][m16] = rs;
    #pragma unroll
    for (int gt = 0; gt < 8; ++gt)
        #pragma unroll
        for (int rr = 0; rr < 4; ++rr)
            Opw[w][(q * 4 + rr) * 132 + gt * 16 + m16] = acc[gt][rr];
    __syncthreads();

    {
        const int row = t >> 4, k8 = (t & 15) * 8;
        float v[8] = {0.f,0.f,0.f,0.f,0.f,0.f,0.f,0.f};
        #pragma unroll
        for (int sl = 0; sl < 4; ++sl) {
            float4 u0 = *(const float4*)&Opw[sl][row * 132 + k8];
            float4 u1 = *(const float4*)&Opw[sl][row * 132 + k8 + 4];
            v[0] += u0.x; v[1] += u0.y; v[2] += u0.z; v[3] += u0.w;
            v[4] += u1.x; v[5] += u1.y; v[6] += u1.z; v[7] += u1.w;
        }
        const float rst = rsw[0][row] + rsw[1][row] + rsw[2][row] + rsw[3][row];
        const float inv = 1.0f / rst;
        const float4 b0 = *(const float4*)(bias + k8);
        const float4 b1 = *(const float4*)(bias + k8 + 4);
        float4 o0 = { v[0]*inv + b0.x, v[1]*inv + b0.y, v[2]*inv + b0.z, v[3]*inv + b0.w };
        float4 o1 = { v[4]*inv + b1.x, v[5]*inv + b1.y, v[6]*inv + b1.z, v[7]*inv + b1.w };
        float* op = out + ((size_t)(b * NN + ibase + row)) * FF + k8;
        *(float4*)op = o0;
        *(float4*)(op + 4) = o1;
    }
}

extern "C" void kernel_launch(void* const* d_in, const int* in_sizes, int n_in,
                              void* d_out, int out_size, void* d_ws, size_t ws_size,
                              hipStream_t stream) {
    const float* x    = (const float*)d_in[0];
    const float* A    = (const float*)d_in[1];
    const float* W    = (const float*)d_in[2];
    const float* a_w  = (const float*)d_in[3];
    const float* a_b  = (const float*)d_in[4];
    const float* bias = (const float*)d_in[5];
    float* out = (float*)d_out;

    char* ws = (char*)d_ws;
    uint16_t* Ht = (uint16_t*)ws;                   // 2 MB
    float* s = (float*)(ws + 2 * 1024 * 1024);      // 32 KB

    k1_proj<<<BB * (NN / 16), 256, 0, stream>>>(x, W, a_w, a_b, Ht, s);
    k2_attn<<<128 * BB, 256, 0, stream>>>(A, Ht, s, bias, out);
}